// Round 5
// baseline (133.805 us; speedup 1.0000x reference)
//
#include <hip/hip_runtime.h>

#define NBINS 4096
#define CAP 4096
#define BATCH 8
#define MASK_TH 0.01f
#define QQ 0.9f
#define SCAN_T 256
#define CHUNK (NBINS / SCAN_T)   // 16 bins per thread
#define EPSF 1e-8f

__device__ __forceinline__ int bin_of(float t) {
    int b = (int)(t * (float)NBINS);
    return b > NBINS - 1 ? NBINS - 1 : (b < 0 ? 0 : b);
}

// Pass 1: per-batch histogram of valid target values. Branch-free (dummy bin),
// register double-buffered 4x float4 loads, 8 blocks/CU.
__global__ __launch_bounds__(256, 8) void k_hist(const float* __restrict__ tgt,
                                                 int* __restrict__ hist, int nper) {
    __shared__ int lh[NBINS + 1];
    const int b = blockIdx.y;
    for (int i = threadIdx.x; i < NBINS + 1; i += blockDim.x) lh[i] = 0;
    __syncthreads();
    const float4* t4 = (const float4*)(tgt + (size_t)b * nper);
    const int n4 = nper >> 2;
    const int S = gridDim.x * blockDim.x;
    const int base = blockIdx.x * blockDim.x + threadIdx.x;
    const int quads = n4 / (4 * S);
#define H1(t) atomicAdd(&lh[((t) > MASK_TH) ? bin_of(t) : NBINS], 1)
    float4 c0, c1, c2, c3;
    if (quads > 0) {
        c0 = t4[base]; c1 = t4[base + S]; c2 = t4[base + 2 * S]; c3 = t4[base + 3 * S];
    }
    for (int q = 0; q < quads; ++q) {
        float4 n0, n1, n2, n3;
        const bool pf = (q + 1) < quads;
        if (pf) {
            const int i = base + (q + 1) * 4 * S;
            n0 = t4[i]; n1 = t4[i + S]; n2 = t4[i + 2 * S]; n3 = t4[i + 3 * S];
        }
        H1(c0.x); H1(c0.y); H1(c0.z); H1(c0.w);
        H1(c1.x); H1(c1.y); H1(c1.z); H1(c1.w);
        H1(c2.x); H1(c2.y); H1(c2.z); H1(c2.w);
        H1(c3.x); H1(c3.y); H1(c3.z); H1(c3.w);
        if (pf) { c0 = n0; c1 = n1; c2 = n2; c3 = n3; }
    }
    for (int i = base + quads * 4 * S; i < n4; i += S) {
        float4 v = t4[i];
        H1(v.x); H1(v.y); H1(v.z); H1(v.w);
    }
#undef H1
    __syncthreads();
    for (int i = threadIdx.x; i < NBINS; i += blockDim.x) {
        int c = lh[i];
        if (c) atomicAdd(&hist[b * NBINS + i], c);
    }
}

// Pass 2: per batch, find bins holding order statistics k_lo, k_hi.
// Also zeroes out[0]. sel_i[b*4+{0..3}] = b_lo, b_hi, klo_rel, khi_rel.
__global__ void k_scan(const int* __restrict__ hist, int* __restrict__ sel_i,
                       float* __restrict__ sel_f, float* __restrict__ out, int nper) {
    const int b = blockIdx.x;
    const int tid = threadIdx.x;
    if (b == 0 && tid == 0) out[0] = 0.f;
    __shared__ int lh[NBINS];
    __shared__ int csum[SCAN_T];
    __shared__ int s_blo, s_bhi, s_base_lo;
    const int* h = hist + b * NBINS;
    for (int i = tid; i < NBINS; i += SCAN_T) lh[i] = h[i];
    __syncthreads();
    int mysum = 0;
    #pragma unroll
    for (int j = 0; j < CHUNK; ++j) mysum += lh[tid * CHUNK + j];
    csum[tid] = mysum;
    __syncthreads();
    for (int off = 1; off < SCAN_T; off <<= 1) {
        int v = (tid >= off) ? csum[tid - off] : 0;
        __syncthreads();
        csum[tid] += v;
        __syncthreads();
    }
    const int nv = csum[SCAN_T - 1];
    if (nv <= 0) {
        if (tid == 0) {
            sel_i[b * 4 + 0] = -1;
            sel_i[b * 4 + 1] = -1;
            sel_i[b * 4 + 2] = 0;
            sel_i[b * 4 + 3] = 0;
            sel_f[b * 2 + 0] = 0.f;
        }
        return;
    }
    float pos = (float)(nper - nv) + QQ * (float)(nv - 1);
    float fl = floorf(pos);
    int lo = (int)fl;
    int hi = (int)ceilf(pos);
    lo = lo < 0 ? 0 : (lo > nper - 1 ? nper - 1 : lo);
    hi = hi < 0 ? 0 : (hi > nper - 1 ? nper - 1 : hi);
    float frac = pos - fl;
    int klo = lo - (nper - nv);
    int khi = hi - (nper - nv);
    if (klo < 0) klo = 0;
    if (khi < 0) khi = 0;
    if (klo > nv - 1) klo = nv - 1;
    if (khi > nv - 1) khi = nv - 1;

    int cum = csum[tid] - mysum;
    #pragma unroll
    for (int j = 0; j < CHUNK; ++j) {
        int c = lh[tid * CHUNK + j];
        if (c > 0) {
            if (klo >= cum && klo < cum + c) { s_blo = tid * CHUNK + j; s_base_lo = cum; }
            if (khi >= cum && khi < cum + c) { s_bhi = tid * CHUNK + j; }
        }
        cum += c;
    }
    __syncthreads();
    if (tid == 0) {
        sel_i[b * 4 + 0] = s_blo;
        sel_i[b * 4 + 1] = s_bhi;
        sel_i[b * 4 + 2] = klo - s_base_lo;
        sel_i[b * 4 + 3] = khi - s_base_lo;
        sel_f[b * 2 + 0] = frac;
    }
}

// Pass 3 (fused): definite hot/bg e2 sums + counts; collect ambiguous (t,e2).
// Register double-buffered: iteration q+1's 8 float4 loads issued before
// consuming iteration q's. Main path branch-free; ambiguous behind __any.
__global__ __launch_bounds__(256, 4) void k_fused(
        const float* __restrict__ pred, const float* __restrict__ tgt,
        const int* __restrict__ sel_i, int* __restrict__ cnt,
        float* __restrict__ buf_t, float* __restrict__ buf_e,
        float* __restrict__ acc, int nper) {
    const int b = blockIdx.y;
    const int b_lo = sel_i[b * 4 + 0];
    const int b_hi = sel_i[b * 4 + 1];
    const float4* t4 = (const float4*)(tgt + (size_t)b * nper);
    const float4* p4 = (const float4*)(pred + (size_t)b * nper);
    const int n4 = nper >> 2;
    const int S = gridDim.x * blockDim.x;
    const int base = blockIdx.x * blockDim.x + threadIdx.x;
    const int quads = n4 / (4 * S);
    float hs = 0.f, bs = 0.f, hc = 0.f, bc = 0.f;

#define E1(j, tt, pp) { \
        float t = (tt); \
        float e = (pp) - t; \
        float e2 = e * e; \
        int bn = bin_of(t); \
        bool valid = t > MASK_TH; \
        bool hot = valid && (bn > b_hi); \
        bool bg  = valid && (bn < b_lo); \
        hs += hot ? e2 : 0.f; hc += hot ? 1.f : 0.f; \
        bs += bg  ? e2 : 0.f; bc += bg  ? 1.f : 0.f; \
        ambBits |= (valid && !(hot || bg)) ? (1 << (j)) : 0; \
    }
#define A1(j, tt, pp) if (ambBits & (1 << (j))) { \
        float t = (tt); \
        float e = (pp) - t; \
        float e2 = e * e; \
        int k = atomicAdd(&cnt[b], 1); \
        if (k < CAP) { buf_t[(size_t)b * CAP + k] = t; buf_e[(size_t)b * CAP + k] = e2; } \
    }
#define PROC(T0, T1, T2, T3, P0, P1, P2, P3) { \
        int ambBits = 0; \
        E1(0,  T0.x, P0.x); E1(1,  T0.y, P0.y); E1(2,  T0.z, P0.z); E1(3,  T0.w, P0.w); \
        E1(4,  T1.x, P1.x); E1(5,  T1.y, P1.y); E1(6,  T1.z, P1.z); E1(7,  T1.w, P1.w); \
        E1(8,  T2.x, P2.x); E1(9,  T2.y, P2.y); E1(10, T2.z, P2.z); E1(11, T2.w, P2.w); \
        E1(12, T3.x, P3.x); E1(13, T3.y, P3.y); E1(14, T3.z, P3.z); E1(15, T3.w, P3.w); \
        if (__any(ambBits != 0)) { \
            A1(0,  T0.x, P0.x); A1(1,  T0.y, P0.y); A1(2,  T0.z, P0.z); A1(3,  T0.w, P0.w); \
            A1(4,  T1.x, P1.x); A1(5,  T1.y, P1.y); A1(6,  T1.z, P1.z); A1(7,  T1.w, P1.w); \
            A1(8,  T2.x, P2.x); A1(9,  T2.y, P2.y); A1(10, T2.z, P2.z); A1(11, T2.w, P2.w); \
            A1(12, T3.x, P3.x); A1(13, T3.y, P3.y); A1(14, T3.z, P3.z); A1(15, T3.w, P3.w); \
        } \
    }

    float4 ct0, ct1, ct2, ct3, cp0, cp1, cp2, cp3;
    if (quads > 0) {
        ct0 = t4[base];         ct1 = t4[base + S];
        ct2 = t4[base + 2 * S]; ct3 = t4[base + 3 * S];
        cp0 = p4[base];         cp1 = p4[base + S];
        cp2 = p4[base + 2 * S]; cp3 = p4[base + 3 * S];
    }
    for (int q = 0; q < quads; ++q) {
        float4 nt0, nt1, nt2, nt3, np0, np1, np2, np3;
        const bool pf = (q + 1) < quads;
        if (pf) {
            const int i = base + (q + 1) * 4 * S;
            nt0 = t4[i];         nt1 = t4[i + S];
            nt2 = t4[i + 2 * S]; nt3 = t4[i + 3 * S];
            np0 = p4[i];         np1 = p4[i + S];
            np2 = p4[i + 2 * S]; np3 = p4[i + 3 * S];
        }
        PROC(ct0, ct1, ct2, ct3, cp0, cp1, cp2, cp3);
        if (pf) {
            ct0 = nt0; ct1 = nt1; ct2 = nt2; ct3 = nt3;
            cp0 = np0; cp1 = np1; cp2 = np2; cp3 = np3;
        }
    }
    for (int i = base + quads * 4 * S; i < n4; i += S) {
        float4 t0 = t4[i];
        float4 p0 = p4[i];
        int ambBits = 0;
        E1(0, t0.x, p0.x); E1(1, t0.y, p0.y); E1(2, t0.z, p0.z); E1(3, t0.w, p0.w);
        if (__any(ambBits != 0)) {
            A1(0, t0.x, p0.x); A1(1, t0.y, p0.y); A1(2, t0.z, p0.z); A1(3, t0.w, p0.w);
        }
    }
#undef E1
#undef A1
#undef PROC

    #pragma unroll
    for (int off = 32; off > 0; off >>= 1) {
        hs += __shfl_down(hs, off);
        bs += __shfl_down(bs, off);
        hc += __shfl_down(hc, off);
        bc += __shfl_down(bc, off);
    }
    __shared__ float sh[4][4];
    const int wid = threadIdx.x >> 6;
    const int lane = threadIdx.x & 63;
    if (lane == 0) { sh[wid][0] = hs; sh[wid][1] = bs; sh[wid][2] = hc; sh[wid][3] = bc; }
    __syncthreads();
    if (threadIdx.x == 0) {
        float a0 = 0, a1 = 0, a2 = 0, a3 = 0;
        const int nw = blockDim.x >> 6;
        for (int w = 0; w < nw; ++w) { a0 += sh[w][0]; a1 += sh[w][1]; a2 += sh[w][2]; a3 += sh[w][3]; }
        atomicAdd(&acc[b * 4 + 0], a0);
        atomicAdd(&acc[b * 4 + 1], a1);
        atomicAdd(&acc[b * 4 + 2], a2);
        atomicAdd(&acc[b * 4 + 3], a3);
    }
}

// Pass 4: per batch — exact rank select among candidates, classify them,
// combine with definite sums, atomicAdd contribution into out[0].
__global__ void k_finish(const int* __restrict__ sel_i, const float* __restrict__ sel_f,
                         const int* __restrict__ cnt, const float* __restrict__ buf_t,
                         const float* __restrict__ buf_e, const float* __restrict__ acc,
                         float* __restrict__ out) {
    __shared__ float st[CAP];
    __shared__ float vlo, vhi;
    __shared__ float red[16][4];
    const int b = blockIdx.x;
    const int b_lo = sel_i[b * 4 + 0];
    int n = (b_lo < 0) ? 0 : cnt[b];
    if (n > CAP) n = CAP;
    for (int i = threadIdx.x; i < n; i += blockDim.x) st[i] = buf_t[(size_t)b * CAP + i];
    if (threadIdx.x == 0) { vlo = 0.f; vhi = 0.f; }
    __syncthreads();
    const int klo = sel_i[b * 4 + 2];
    const int khi = sel_i[b * 4 + 3];
    for (int i = threadIdx.x; i < n; i += blockDim.x) {
        float x = st[i];
        int r = 0;
        for (int j = 0; j < n; ++j) {
            float y = st[j];
            r += (y < x) || (y == x && j < i);
        }
        if (r == klo) vlo = x;
        if (r == khi) vhi = x;
    }
    __syncthreads();
    const float frac = sel_f[b * 2 + 0];
    const float thresh = (b_lo < 0) ? MASK_TH : (vlo + frac * (vhi - vlo));
    float hs = 0.f, bs = 0.f, hc = 0.f, bc = 0.f;
    for (int i = threadIdx.x; i < n; i += blockDim.x) {
        float t = st[i];
        float e2 = buf_e[(size_t)b * CAP + i];
        if (t > thresh) { hs += e2; hc += 1.f; }
        else            { bs += e2; bc += 1.f; }
    }
    #pragma unroll
    for (int off = 32; off > 0; off >>= 1) {
        hs += __shfl_down(hs, off);
        bs += __shfl_down(bs, off);
        hc += __shfl_down(hc, off);
        bc += __shfl_down(bc, off);
    }
    const int wid = threadIdx.x >> 6;
    const int lane = threadIdx.x & 63;
    if (lane == 0) { red[wid][0] = hs; red[wid][1] = bs; red[wid][2] = hc; red[wid][3] = bc; }
    __syncthreads();
    if (threadIdx.x == 0) {
        float a0 = 0, a1 = 0, a2 = 0, a3 = 0;
        const int nw = blockDim.x >> 6;
        for (int w = 0; w < nw; ++w) { a0 += red[w][0]; a1 += red[w][1]; a2 += red[w][2]; a3 += red[w][3]; }
        float th = acc[b * 4 + 0] + a0;
        float tb = acc[b * 4 + 1] + a1;
        float nh = acc[b * 4 + 2] + a2;
        float nb = acc[b * 4 + 3] + a3;
        float hl = th / (nh + EPSF);
        float bl = tb / (nb + EPSF);
        atomicAdd(out, (5.0f * hl + bl) * (1.0f / (float)BATCH));
    }
}

extern "C" void kernel_launch(void* const* d_in, const int* in_sizes, int n_in,
                              void* d_out, int out_size, void* d_ws, size_t ws_size,
                              hipStream_t stream) {
    const float* pred = (const float*)d_in[0];
    const float* tgt  = (const float*)d_in[1];
    float* out = (float*)d_out;
    const int total = in_sizes[0];
    const int nper = total / BATCH;

    int*   hist  = (int*)d_ws;                      // B*NBINS ints
    int*   cnt   = hist + BATCH * NBINS;            // B ints
    int*   sel_i = cnt + BATCH;                     // B*4 ints
    float* sel_f = (float*)(sel_i + BATCH * 4);     // B*2 floats
    float* acc   = sel_f + BATCH * 2;               // B*4 floats
    float* buf_t = acc + BATCH * 4;                 // B*CAP floats
    float* buf_e = buf_t + BATCH * CAP;             // B*CAP floats

    const size_t zero_bytes = (size_t)((char*)buf_t - (char*)d_ws);
    hipMemsetAsync(d_ws, 0, zero_bytes, stream);

    k_hist  <<<dim3(256, BATCH), 256, 0, stream>>>(tgt, hist, nper);
    k_scan  <<<BATCH, SCAN_T, 0, stream>>>(hist, sel_i, sel_f, out, nper);
    k_fused <<<dim3(128, BATCH), 256, 0, stream>>>(pred, tgt, sel_i, cnt, buf_t, buf_e, acc, nper);
    k_finish<<<BATCH, 1024, 0, stream>>>(sel_i, sel_f, cnt, buf_t, buf_e, acc, out);
}